// Round 1
// baseline (1258.400 us; speedup 1.0000x reference)
//
#include <hip/hip_runtime.h>

#define BB 8
#define HH 32
#define SS 4096
#define HD 128
#define DD 4096
#define KV 4097
#define CAND 3585
#define KEEP 516

// ---------------------------------------------------------------------------
// ws layout (floats):
//   0        q      [B*H*HD]   = 32768   (atomic accum -> memset)
//   32768    k_new  [B*H*HD]   = 32768   (atomic accum -> memset)
//   65536    v_new  [B*H*HD]   = 32768   (atomic accum -> memset)
//   98304    ctx    [B*H*HD]   = 32768
//   131072   probs  [B*H*KV]   = 1048832
//   1179904  topk   [B*4] ints
// total ~4.72 MB
// ---------------------------------------------------------------------------

// out[b][n] += sum_k in[b][k] * W[k][n]; K split across blockIdx.y (atomics).
// blockIdx.z selects W0/W1/W2 and output slab z*32768.
__global__ __launch_bounds__(256) void gemv8(
    const float* __restrict__ in, const float* __restrict__ W0,
    const float* __restrict__ W1, const float* __restrict__ W2,
    float* __restrict__ out)
{
    const float* W = (blockIdx.z == 0) ? W0 : ((blockIdx.z == 1) ? W1 : W2);
    float* o = out + (size_t)blockIdx.z * (BB * DD);

    const int KCH = 128;
    int k0 = blockIdx.y * KCH;
    int n = blockIdx.x * 512 + 2 * threadIdx.x;

    __shared__ float hsh[BB * 128];
    for (int i = threadIdx.x; i < BB * KCH; i += 256) {
        int b = i >> 7, kk = i & 127;
        hsh[i] = in[b * DD + k0 + kk];
    }
    __syncthreads();

    float accx[BB], accy[BB];
#pragma unroll
    for (int b = 0; b < BB; ++b) { accx[b] = 0.f; accy[b] = 0.f; }

    for (int kk = 0; kk < KCH; ++kk) {
        float2 w = *(const float2*)(W + (size_t)(k0 + kk) * DD + n);
#pragma unroll
        for (int b = 0; b < BB; ++b) {
            float h = hsh[b * KCH + kk];
            accx[b] += h * w.x;
            accy[b] += h * w.y;
        }
    }
#pragma unroll
    for (int b = 0; b < BB; ++b) {
        atomicAdd(&o[b * DD + n], accx[b]);
        atomicAdd(&o[b * DD + n + 1], accy[b]);
    }
}

// RoPE in place at position S on q and k_new. 2*8*32*64 = 32768 threads.
__global__ __launch_bounds__(256) void rope_kernel(float* __restrict__ q,
                                                   float* __restrict__ k)
{
    int idx = blockIdx.x * 256 + threadIdx.x;   // [0, 32768)
    int j = idx & 63;
    int bh = (idx >> 6) & 255;
    int tsel = idx >> 14;                        // 0 = q, 1 = k
    float* p = (tsel ? k : q) + bh * HD;

    double ang = 4096.0 * pow(10000.0, -(double)j / 64.0);
    double s, c;
    sincos(ang, &s, &c);
    float sf = (float)s, cf = (float)c;

    float x0 = p[j], x1 = p[j + 64];
    p[j]      = x0 * cf - x1 * sf;
    p[j + 64] = x1 * cf + x0 * sf;
}

// One block per (b,h). 1024 threads = 16 waves.
__global__ __launch_bounds__(1024) void attn_kernel(
    const float* __restrict__ pk, const float* __restrict__ pv,
    const float* __restrict__ qws, const float* __restrict__ kns,
    const float* __restrict__ vns, float* __restrict__ probs,
    float* __restrict__ ctx)
{
    __shared__ float sc[4104];
    __shared__ float red[32];
    __shared__ float ctxp[16 * 128];

    int bh = blockIdx.x;
    int tid = threadIdx.x;
    int lane = tid & 63, w = tid >> 6;

    float2 q2 = *(const float2*)(qws + bh * HD + 2 * lane);
    const float* kbase = pk + (size_t)bh * SS * HD;
    const float* kn = kns + bh * HD;
    const float scale = 0.08838834764831843f;   // 1/sqrt(128)

    float mloc = -1e30f;
    for (int i0 = w * 4; i0 < KV; i0 += 64) {
        float2 kb[4];
#pragma unroll
        for (int u = 0; u < 4; ++u) {
            int i = i0 + u;
            if (i < KV) {
                const float* kp = (i < SS) ? (kbase + (size_t)i * HD) : kn;
                kb[u] = *(const float2*)(kp + 2 * lane);
            }
        }
#pragma unroll
        for (int u = 0; u < 4; ++u) {
            int i = i0 + u;
            if (i < KV) {
                float d = q2.x * kb[u].x + q2.y * kb[u].y;
#pragma unroll
                for (int off = 1; off < 64; off <<= 1) d += __shfl_xor(d, off, 64);
                d *= scale;
                if (lane == 0) sc[i] = d;
                mloc = fmaxf(mloc, d);
            }
        }
    }
    if (lane == 0) red[w] = mloc;
    __syncthreads();
    if (tid == 0) {
        float m = red[0];
        for (int i = 1; i < 16; ++i) m = fmaxf(m, red[i]);
        red[16] = m;
    }
    __syncthreads();
    float m = red[16];

    float ls = 0.f;
    for (int i = tid; i < KV; i += 1024) {
        float p = __expf(sc[i] - m);
        sc[i] = p;
        ls += p;
    }
#pragma unroll
    for (int off = 1; off < 64; off <<= 1) ls += __shfl_xor(ls, off, 64);
    __syncthreads();              // all sc[] updates done
    if (lane == 0) red[w] = ls;
    __syncthreads();
    if (tid == 0) {
        float l = 0.f;
        for (int i = 0; i < 16; ++i) l += red[i];
        red[17] = 1.0f / l;
    }
    __syncthreads();
    float invl = red[17];

    for (int i = tid; i < KV; i += 1024)
        probs[(size_t)bh * KV + i] = sc[i] * invl;

    const float* vbase = pv + (size_t)bh * SS * HD;
    const float* vn = vns + bh * HD;
    float ax = 0.f, ay = 0.f;
    for (int i0 = w * 4; i0 < KV; i0 += 64) {
        float2 vb[4];
        float pp[4];
#pragma unroll
        for (int u = 0; u < 4; ++u) {
            int i = i0 + u;
            if (i < KV) {
                const float* vp = (i < SS) ? (vbase + (size_t)i * HD) : vn;
                vb[u] = *(const float2*)(vp + 2 * lane);
                pp[u] = sc[i];
            }
        }
#pragma unroll
        for (int u = 0; u < 4; ++u) {
            int i = i0 + u;
            if (i < KV) { ax += pp[u] * vb[u].x; ay += pp[u] * vb[u].y; }
        }
    }
    ctxp[w * 128 + 2 * lane] = ax;
    ctxp[w * 128 + 2 * lane + 1] = ay;
    __syncthreads();
    if (tid < 128) {
        float s = 0.f;
        for (int w2 = 0; w2 < 16; ++w2) s += ctxp[w2 * 128 + tid];
        ctx[bh * HD + tid] = s * invl;
    }
}

// One block per batch. imp = mean_h probs + prev; top-4 over [0, CAND);
// writes sorted topk idx to ws and imp_kept (516) to d_out.
__global__ __launch_bounds__(1024) void imp_topk(
    const float* __restrict__ probs, const float* __restrict__ prev,
    float* __restrict__ impkept, int* __restrict__ topk)
{
    __shared__ float imp[4104];
    __shared__ float rv[16];
    __shared__ int ri[16];
    __shared__ int kidx[4];
    __shared__ float kval[4];

    int b = blockIdx.x;
    int tid = threadIdx.x;
    int lane = tid & 63, w = tid >> 6;

    for (int i = tid; i < KV; i += 1024) {
        float s = 0.f;
#pragma unroll
        for (int h = 0; h < HH; ++h)
            s += probs[(size_t)(b * HH + h) * KV + i];
        s *= (1.0f / 32.0f);
        if (i < SS) s += prev[b * SS + i];
        imp[i] = s;
    }
    __syncthreads();

    for (int r = 0; r < 4; ++r) {
        float bv = -1e30f;
        int bi = 0x7fffffff;
        for (int i = tid; i < CAND; i += 1024) {
            float v = imp[i];
            if (v > bv || (v == bv && i < bi)) { bv = v; bi = i; }
        }
#pragma unroll
        for (int off = 1; off < 64; off <<= 1) {
            float ov = __shfl_xor(bv, off, 64);
            int oi = __shfl_xor(bi, off, 64);
            if (ov > bv || (ov == bv && oi < bi)) { bv = ov; bi = oi; }
        }
        if (lane == 0) { rv[w] = bv; ri[w] = bi; }
        __syncthreads();
        if (tid == 0) {
            float xv = rv[0]; int xi = ri[0];
            for (int j = 1; j < 16; ++j)
                if (rv[j] > xv || (rv[j] == xv && ri[j] < xi)) { xv = rv[j]; xi = ri[j]; }
            kidx[r] = xi; kval[r] = xv;
            imp[xi] = -1e30f;
        }
        __syncthreads();
    }
    if (tid == 0) {
        // sort 4 (idx,val) pairs ascending by idx
        for (int i = 0; i < 3; ++i)
            for (int j = 0; j < 3 - i; ++j)
                if (kidx[j] > kidx[j + 1]) {
                    int ti = kidx[j]; kidx[j] = kidx[j + 1]; kidx[j + 1] = ti;
                    float tv = kval[j]; kval[j] = kval[j + 1]; kval[j + 1] = tv;
                }
        for (int i = 0; i < 4; ++i) topk[b * 4 + i] = kidx[i];
    }
    __syncthreads();
    if (tid < 4) impkept[b * KEEP + tid] = kval[tid];
    for (int t = tid; t < 512; t += 1024)
        impkept[b * KEEP + 4 + t] = imp[CAND + t];
}

// Gather k_ev / v_ev. One float4 per thread.
__global__ __launch_bounds__(256) void gather_kv(
    const float* __restrict__ pk, const float* __restrict__ pv,
    const float* __restrict__ kn, const float* __restrict__ vn,
    const int* __restrict__ topk, float* __restrict__ out)
{
    const size_t per = (size_t)BB * HH * KEEP * (HD / 4);   // 4227072
    size_t t = (size_t)blockIdx.x * 256 + threadIdx.x;
    int sel = (t >= per) ? 1 : 0;
    if (sel) t -= per;

    int d4 = (int)(t & 31);
    size_t rest = t >> 5;                 // (b*H + h)*KEEP + j
    int j = (int)(rest % KEEP);
    size_t bh = rest / KEEP;
    int b = (int)(bh >> 5);

    int idx = (j < 4) ? topk[b * 4 + j] : (3581 + j);
    const float* src;
    if (idx < SS)
        src = (sel ? pv : pk) + (bh * SS + idx) * HD;
    else
        src = (sel ? vn : kn) + bh * HD;

    float4 val = *(const float4*)(src + d4 * 4);
    float* dst = out + 32768 + (size_t)sel * (BB * HH * KEEP * HD)
               + rest * HD + d4 * 4;
    *(float4*)dst = val;
}

extern "C" void kernel_launch(void* const* d_in, const int* in_sizes, int n_in,
                              void* d_out, int out_size, void* d_ws, size_t ws_size,
                              hipStream_t stream)
{
    const float* hid  = (const float*)d_in[0];
    const float* pk   = (const float*)d_in[1];
    const float* pv   = (const float*)d_in[2];
    const float* Wq   = (const float*)d_in[3];
    const float* Wk   = (const float*)d_in[4];
    const float* Wv   = (const float*)d_in[5];
    const float* Wo   = (const float*)d_in[6];
    const float* prev = (const float*)d_in[7];

    float* out = (float*)d_out;
    float* ws  = (float*)d_ws;

    float* qws   = ws;
    float* kns   = ws + 32768;
    float* vns   = ws + 65536;
    float* ctx   = ws + 98304;
    float* probs = ws + 131072;
    int*   topk  = (int*)(ws + 131072 + (size_t)BB * HH * KV);

    // zero atomic-accumulation targets (ws/d_out are poisoned every call)
    hipMemsetAsync(ws, 0, 4 * 32768 * sizeof(float), stream);
    hipMemsetAsync(out, 0, 32768 * sizeof(float), stream);

    // q,k,v projections
    gemv8<<<dim3(8, 32, 3), 256, 0, stream>>>(hid, Wq, Wk, Wv, qws);
    // RoPE on q, k_new
    rope_kernel<<<128, 256, 0, stream>>>(qws, kns);
    // attention over 4097 kv positions
    attn_kernel<<<256, 1024, 0, stream>>>(pk, pv, qws, kns, vns, probs, ctx);
    // importance + top-4 + imp_kept
    float* impkept = out + 32768 + 2 * (size_t)BB * HH * KEEP * HD;
    imp_topk<<<8, 1024, 0, stream>>>(probs, prev, impkept, topk);
    // evicted-cache gather
    gather_kv<<<33024, 256, 0, stream>>>(pk, pv, kns, vns, topk, out);
    // output projection
    gemv8<<<dim3(8, 32, 1), 256, 0, stream>>>(ctx, Wo, Wo, Wo, out);
}